// Round 1
// baseline (1354.104 us; speedup 1.0000x reference)
//
#include <hip/hip_runtime.h>

// Problem: x[256,1,58,58] --conv5x5(w1:64ch)--> [256,64,54,54] --maxpool2-->
// [256,64,27,27] --conv5x5(w2:128ch)--> [256,128,23,23] --linear(lw,lb:10)-->
// out[256,23,23,10]  (all f32)

#define NB 256

// ---------------- Kernel 1: conv1 (C=1) + 2x2 maxpool, fused ----------------
// One block per batch image. Whole 58x58 input (13.5 KB) + w1 (6.4 KB) in LDS.
__global__ __launch_bounds__(256) void conv1_pool_kernel(
    const float* __restrict__ x, const float* __restrict__ w1,
    float* __restrict__ pooled)
{
    __shared__ float xs[58 * 58];
    __shared__ float wsh[64 * 25];
    const int b = blockIdx.x;
    const int tid = threadIdx.x;
    const float* xb = x + b * 58 * 58;
    for (int i = tid; i < 58 * 58; i += 256) xs[i] = xb[i];
    for (int i = tid; i < 64 * 25; i += 256) wsh[i] = w1[i];
    __syncthreads();

    // 64 oc * 27 * 27 = 46656 pooled outputs per image
    for (int idx = tid; idx < 64 * 27 * 27; idx += 256) {
        int oc = idx / 729;
        int pos = idx - oc * 729;
        int ph = pos / 27;
        int pw = pos - ph * 27;

        float wreg[25];
#pragma unroll
        for (int k = 0; k < 25; ++k) wreg[k] = wsh[oc * 25 + k];

        // 6x6 input patch covers the 2x2 conv window positions
        float p[6][6];
        const int h0 = 2 * ph, w0 = 2 * pw;
#pragma unroll
        for (int r = 0; r < 6; ++r)
#pragma unroll
            for (int c = 0; c < 6; ++c)
                p[r][c] = xs[(h0 + r) * 58 + (w0 + c)];

        float m = -1e30f;
#pragma unroll
        for (int dy = 0; dy < 2; ++dy)
#pragma unroll
            for (int dx = 0; dx < 2; ++dx) {
                float acc = 0.f;
#pragma unroll
                for (int kh = 0; kh < 5; ++kh)
#pragma unroll
                    for (int kw = 0; kw < 5; ++kw)
                        acc += p[dy + kh][dx + kw] * wreg[kh * 5 + kw];
                m = fmaxf(m, acc);
            }
        pooled[(b * 64 + oc) * 729 + pos] = m;
    }
}

// ------------- Kernel 2: conv2 (64->128, 5x5) + linear (128->10) ------------
// Implicit GEMM: C[M=529 spatial, N=128 oc] = im2col(pooled) x w2, K = 64*25.
// Grid (9 M-tiles of 64 spatial, 256 batches). Block 256 = 16(tm) x 16(tn).
// Thread tile: 4 spatial x 8 oc = 32 f32 accumulators.
// Per input channel: stage 27x27 plane (xs) + w2[:,ic,:,:] as [25][132] (wsh).
// Epilogue: conv tile -> LDS -> 10-wide linear -> d_out.
__global__ __launch_bounds__(256) void conv2_linear_kernel(
    const float* __restrict__ pooled, const float* __restrict__ w2,
    const float* __restrict__ lw, const float* __restrict__ lb,
    float* __restrict__ out)
{
    __shared__ float smem[64 * 132];     // 33.8 KB; phases reuse it
    float* xs  = smem;                   // [729]    (one ic plane)
    float* wsh = smem + 736;             // [25*132] (pad 128->132: kills the
                                         //  25-way same-bank ds_write)

    const int mt = blockIdx.x, b = blockIdx.y;
    const int tid = threadIdx.x;
    const int tm = tid >> 4, tn = tid & 15;

    // this thread's 4 spatial positions (clamped; stores guarded)
    int off[4];
    bool valid[4];
    const int pbase = mt * 64 + tm * 4;
#pragma unroll
    for (int s = 0; s < 4; ++s) {
        int p = pbase + s;
        valid[s] = (p < 529);
        int pc = valid[s] ? p : 528;
        int oh = pc / 23, ow = pc - oh * 23;
        off[s] = oh * 27 + ow;
    }

    float acc[4][8];
#pragma unroll
    for (int s = 0; s < 4; ++s)
#pragma unroll
        for (int j = 0; j < 8; ++j) acc[s][j] = 0.f;

    for (int ic = 0; ic < 64; ++ic) {
        __syncthreads();  // previous iteration's reads done before overwrite
        for (int i = tid; i < 729; i += 256)
            xs[i] = pooled[(b * 64 + ic) * 729 + i];
        // w2[oc][ic][k] -> wsh[k*132 + oc]; global reads in 25-float runs
        for (int i = tid; i < 3200; i += 256) {
            int oc = i / 25, k = i - oc * 25;
            wsh[k * 132 + oc] = w2[oc * 1600 + ic * 25 + k];
        }
        __syncthreads();

#pragma unroll
        for (int kh = 0; kh < 5; ++kh) {
#pragma unroll
            for (int kw = 0; kw < 5; ++kw) {
                const int kidx = kh * 5 + kw;
                const float4* wp =
                    (const float4*)&wsh[kidx * 132 + tn * 8];
                const float4 wa = wp[0], wb = wp[1];
                float av[4];
#pragma unroll
                for (int s = 0; s < 4; ++s)
                    av[s] = xs[off[s] + kh * 27 + kw];  // 16-lane broadcast
#pragma unroll
                for (int s = 0; s < 4; ++s) {
                    acc[s][0] += av[s] * wa.x;
                    acc[s][1] += av[s] * wa.y;
                    acc[s][2] += av[s] * wa.z;
                    acc[s][3] += av[s] * wa.w;
                    acc[s][4] += av[s] * wb.x;
                    acc[s][5] += av[s] * wb.y;
                    acc[s][6] += av[s] * wb.z;
                    acc[s][7] += av[s] * wb.w;
                }
            }
        }
    }

    __syncthreads();
    // conv tile -> LDS (reuse smem): tile[sp][oc], pad 132
    float* tile = smem;
#pragma unroll
    for (int s = 0; s < 4; ++s) {
        const int sp = tm * 4 + s;
#pragma unroll
        for (int j = 0; j < 8; ++j)
            tile[sp * 132 + tn * 8 + j] = acc[s][j];
    }
    __syncthreads();

    // linear: 64 spatial x 10 outputs
    for (int i = tid; i < 640; i += 256) {
        int sp = i / 10, o = i - sp * 10;
        int p = mt * 64 + sp;
        if (p >= 529) continue;
        float v = lb[o];
        const float* lwo = lw + o * 128;
        const float* tr = tile + sp * 132;
#pragma unroll
        for (int c = 0; c < 128; ++c) v += tr[c] * lwo[c];
        out[(b * 529 + p) * 10 + o] = v;
    }
}

extern "C" void kernel_launch(void* const* d_in, const int* in_sizes, int n_in,
                              void* d_out, int out_size, void* d_ws, size_t ws_size,
                              hipStream_t stream) {
    const float* x  = (const float*)d_in[0];  // [256,1,58,58]
    const float* w1 = (const float*)d_in[1];  // [64,1,5,5]
    const float* w2 = (const float*)d_in[2];  // [128,64,5,5]
    const float* lw = (const float*)d_in[3];  // [10,128]
    const float* lb = (const float*)d_in[4];  // [10]
    float* out = (float*)d_out;               // [256,23,23,10]
    float* pooled = (float*)d_ws;             // [256,64,27,27] f32 = 47.8 MB

    conv1_pool_kernel<<<NB, 256, 0, stream>>>(x, w1, pooled);
    conv2_linear_kernel<<<dim3(9, NB), 256, 0, stream>>>(pooled, w2, lw, lb, out);
}

// Round 2
// 104.465 us; speedup vs baseline: 12.9623x; 12.9623x over previous
//
#include <hip/hip_runtime.h>

// x[256,1,58,58] -> conv5x5(64) -> maxpool2 -> [256,64,27,27]
//   -> conv5x5(128) -> [256,128,23,23] -> linear(10) -> out[256,23,23,10] f32
//
// Strategy: conv2 (95% of FLOPs) via bf16 MFMA 16x16x32 implicit GEMM.
//   A[sp 529][k=ic 64] per (kh,kw) slice from channels-last pooled image in LDS
//   B[k=ic][n=oc 128]  from transposed weights w2b[kk][oc][ic] in LDS (dbuf)
//   25 slices x 2 k-halves = 50 MFMA K-steps (exactly K=1600, no padding)
// Linear fused via bf16 LDS round-trip + MFMA (K=128, N=10 padded to 16).

typedef __attribute__((ext_vector_type(8))) short bf16x8;
typedef __attribute__((ext_vector_type(4))) float f32x4;
typedef __attribute__((ext_vector_type(4))) unsigned int u32x4;

#define MFMA16(a, b, c) __builtin_amdgcn_mfma_f32_16x16x32_bf16((a), (b), (c), 0, 0, 0)

static __device__ __forceinline__ unsigned short f2bf(float f) {
    unsigned u = __builtin_bit_cast(unsigned, f);
    u += 0x7FFFu + ((u >> 16) & 1u);   // RNE
    return (unsigned short)(u >> 16);
}

// ---------------- K0: w2[oc128][ic64][25] f32 -> w2b[kk25][oc128][ic64] bf16
__global__ __launch_bounds__(256) void prep_w2(
    const float* __restrict__ w2, unsigned short* __restrict__ w2b)
{
    int e = (blockIdx.x * 256 + threadIdx.x) * 4;   // 204800 elems, 4/thread
    if (e >= 25 * 128 * 64) return;
    int kk = e / 8192;
    int r  = e - kk * 8192;
    int oc = r >> 6, ic = r & 63;
    unsigned long long pack = 0;
#pragma unroll
    for (int j = 0; j < 4; ++j) {
        unsigned short v = f2bf(w2[oc * 1600 + (ic + j) * 25 + kk]);
        pack |= (unsigned long long)v << (16 * j);
    }
    *(unsigned long long*)(w2b + e) = pack;
}

// ---------------- K1: conv1 (C=1) + maxpool2 -> pooled[b][pix729][ic64] bf16
// Thread-per-pixel computes all 64 oc -> 128B contiguous coalesced store.
__global__ __launch_bounds__(256, 3) void conv1_pool(
    const float* __restrict__ x, const float* __restrict__ w1,
    unsigned short* __restrict__ pooled)
{
    __shared__ float xs[3364];        // 58*58
    __shared__ float wsh[64 * 28];    // rows padded 25->28 floats (16B align)
    const int bp = blockIdx.x, b = blockIdx.y, tid = threadIdx.x;
    const float* xb = x + b * 3364;
    for (int i = tid; i < 841; i += 256)
        ((float4*)xs)[i] = ((const float4*)xb)[i];
    for (int i = tid; i < 1600; i += 256) {
        int oc = i / 25, k = i - oc * 25;
        wsh[oc * 28 + k] = w1[i];
    }
    __syncthreads();

    if (tid < 243) {
        const int p = bp * 243 + tid;          // < 729
        const int ph = p / 27, pw = p - ph * 27;
        float patch[6][6];
#pragma unroll
        for (int r = 0; r < 6; ++r)
#pragma unroll
            for (int c = 0; c < 6; ++c)
                patch[r][c] = xs[(2 * ph + r) * 58 + 2 * pw + c];

        unsigned pack[32];
#pragma unroll
        for (int oc = 0; oc < 64; ++oc) {
            const float* wr = &wsh[oc * 28];
            float wv[28];
#pragma unroll
            for (int q = 0; q < 7; ++q)
                *(float4*)&wv[q * 4] = *(const float4*)(wr + q * 4);
            float s00 = 0.f, s01 = 0.f, s10 = 0.f, s11 = 0.f;
#pragma unroll
            for (int kh = 0; kh < 5; ++kh)
#pragma unroll
                for (int kw = 0; kw < 5; ++kw) {
                    float wgt = wv[kh * 5 + kw];
                    s00 += patch[kh][kw] * wgt;
                    s01 += patch[kh][kw + 1] * wgt;
                    s10 += patch[kh + 1][kw] * wgt;
                    s11 += patch[kh + 1][kw + 1] * wgt;
                }
            float m = fmaxf(fmaxf(s00, s01), fmaxf(s10, s11));
            unsigned short hb = f2bf(m);
            if (oc & 1) pack[oc >> 1] |= (unsigned)hb << 16;
            else        pack[oc >> 1]  = hb;
        }
        u32x4* dst = (u32x4*)(pooled + ((size_t)b * 729 + p) * 64);
#pragma unroll
        for (int q = 0; q < 8; ++q) {
            u32x4 v;
            v.x = pack[q * 4 + 0]; v.y = pack[q * 4 + 1];
            v.z = pack[q * 4 + 2]; v.w = pack[q * 4 + 3];
            dst[q] = v;
        }
    }
}

// ---------------- K2: conv2 MFMA + fused linear ----------------
// LDS map (dynamic, 152320 B):
//   main:     xs   [0, 104976)           729 pixel rows x 144B (64 bf16 + pad)
//             wsh  [104976, 141840)      2 x (128 oc rows x 144B)
//   epilogue: econ [0, 147968)           544 sp rows x 272B (128 bf16 + pad)
//   always:   lwT2 [147968, 152320)      16 o rows x 272B
#define XS_OFF   0
#define WS_OFF   104976
#define WSLICE   18432
#define ECON_STR 272
#define LWT_OFF  147968
#define LDS_TOT  152320

__global__ __launch_bounds__(512, 2) void conv2_lin(
    const unsigned short* __restrict__ pooled,
    const unsigned short* __restrict__ w2b,
    const float* __restrict__ lw, const float* __restrict__ lb,
    float* __restrict__ out)
{
    extern __shared__ char lds[];
    const int b = blockIdx.x, tid = threadIdx.x;
    const int lane = tid & 63, w = tid >> 6;        // 8 waves
    const int lane16 = lane & 15, kg = lane >> 4;   // kg = 0..3
    const int ocg = w & 1, mg = w >> 1;             // 2 oc-groups x 4 m-groups
    const int oc0 = ocg * 64;                       // wave owns 64 oc (4 N-tiles)
    const int mstart = (mg == 0) ? 0 : mg * 8 + 1;  // {0,9,17,25}, 9 tiles each

    // ---- stage pooled image -> xs (144B rows) ----
    const unsigned short* src = pooled + (size_t)b * 46656;
    for (int c = tid; c < 5832; c += 512) {
        int p = c >> 3, k8 = c & 7;
        u32x4 v = *(const u32x4*)(src + c * 8);
        *(u32x4*)(lds + XS_OFF + p * 144 + k8 * 16) = v;
    }
    // ---- stage weight slice 0 ----
    for (int c = tid; c < 1024; c += 512) {
        int oc = c >> 3, k8 = c & 7;
        u32x4 v = *(const u32x4*)(w2b + c * 8);
        *(u32x4*)(lds + WS_OFF + oc * 144 + k8 * 16) = v;
    }
    // ---- stage lwT2 bf16 [o16][c128] (272B rows), pad rows zeroed ----
    for (int i = tid; i < 2048; i += 512) {
        int o = i >> 7, cc = i & 127;
        float v = (o < 10) ? lw[o * 128 + cc] : 0.f;
        *(unsigned short*)(lds + LWT_OFF + o * 272 + cc * 2) = f2bf(v);
    }

    // ---- per-lane A base byte-offsets (9 M-tiles) ----
    int abase[9];
#pragma unroll
    for (int mt = 0; mt < 9; ++mt) {
        int sp = (mstart + mt) * 16 + lane16;
        if (sp > 528) sp = 528;                     // clamp loads; stores guarded
        int oh = sp / 23, ow = sp - oh * 23;
        abase[mt] = (oh * 27 + ow) * 144 + kg * 16;
    }
    const int bbase = (oc0 + lane16) * 144 + kg * 16;  // + nt*2304 + khalf*64

    f32x4 acc[9][4];
#pragma unroll
    for (int mt = 0; mt < 9; ++mt)
#pragma unroll
        for (int nt = 0; nt < 4; ++nt)
            acc[mt][nt] = (f32x4){0.f, 0.f, 0.f, 0.f};

    __syncthreads();

    // ---- main K-loop: 25 (kh,kw) slices, dbuf weights, async-stage split ----
    for (int kk = 0; kk < 25; ++kk) {
        const int cur = kk & 1;
        const bool pref = (kk < 24);
        u32x4 st0, st1;
        const int c0 = tid, c1 = tid + 512;
        if (pref) {                       // issue loads early (hide under MFMA)
            const unsigned short* ws = w2b + (kk + 1) * 8192;
            st0 = *(const u32x4*)(ws + c0 * 8);
            st1 = *(const u32x4*)(ws + c1 * 8);
        }

        const int kh = kk / 5, kw = kk - 5 * (kk / 5);
        const int pixoffB = (kh * 27 + kw) * 144;
        const char* wbuf = lds + WS_OFF + cur * WSLICE + bbase;

        bf16x8 bf[2][4];
#pragma unroll
        for (int nt = 0; nt < 4; ++nt) {
            bf[0][nt] = *(const bf16x8*)(wbuf + nt * 2304);
            bf[1][nt] = *(const bf16x8*)(wbuf + nt * 2304 + 64);
        }
#pragma unroll
        for (int mt = 0; mt < 9; ++mt) {
            const char* ap = lds + XS_OFF + abase[mt] + pixoffB;
            bf16x8 a0 = *(const bf16x8*)(ap);
            bf16x8 a1 = *(const bf16x8*)(ap + 64);
#pragma unroll
            for (int nt = 0; nt < 4; ++nt)
                acc[mt][nt] = MFMA16(a0, bf[0][nt], acc[mt][nt]);
#pragma unroll
            for (int nt = 0; nt < 4; ++nt)
                acc[mt][nt] = MFMA16(a1, bf[1][nt], acc[mt][nt]);
        }

        if (pref) {                        // write staged regs late
            char* wd = lds + WS_OFF + (cur ^ 1) * WSLICE;
            int oc = c0 >> 3, k8 = c0 & 7;
            *(u32x4*)(wd + oc * 144 + k8 * 16) = st0;
            oc = c1 >> 3; k8 = c1 & 7;
            *(u32x4*)(wd + oc * 144 + k8 * 16) = st1;
        }
        __syncthreads();
    }

    // ---- epilogue: conv tile -> econ bf16 [544][272B rows] ----
    __syncthreads();   // xs/wsh dead for ALL waves before overwrite
#pragma unroll
    for (int mt = 0; mt < 9; ++mt) {
        const int spb = (mstart + mt) * 16 + kg * 4;
#pragma unroll
        for (int nt = 0; nt < 4; ++nt) {
            const int col = oc0 + nt * 16 + lane16;
#pragma unroll
            for (int r = 0; r < 4; ++r) {
                int sp = spb + r;
                if (sp < 529)
                    *(unsigned short*)(lds + sp * ECON_STR + col * 2) =
                        f2bf(acc[mt][nt][r]);
            }
        }
    }
    __syncthreads();

    // ---- linear via MFMA: out[sp][o] = econ[sp][c] x lwT2[o][c] + lb ----
    const float lbv = (lane16 < 10) ? lb[lane16] : 0.f;
#pragma unroll
    for (int i = 0; i < 5; ++i) {
        const int t = w + 8 * i;             // wave-uniform tile id
        if (t < 34) {
            f32x4 al = (f32x4){0.f, 0.f, 0.f, 0.f};
            const char* arow = lds + (t * 16 + lane16) * ECON_STR + kg * 16;
            const char* brow = lds + LWT_OFF + lane16 * 272 + kg * 16;
#pragma unroll
            for (int ks = 0; ks < 4; ++ks) {
                bf16x8 av = *(const bf16x8*)(arow + ks * 64);
                bf16x8 bv = *(const bf16x8*)(brow + ks * 64);
                al = MFMA16(av, bv, al);
            }
            if (lane16 < 10) {
#pragma unroll
                for (int r = 0; r < 4; ++r) {
                    int sp = t * 16 + kg * 4 + r;
                    if (sp < 529)
                        out[((size_t)b * 529 + sp) * 10 + lane16] = al[r] + lbv;
                }
            }
        }
    }
}

extern "C" void kernel_launch(void* const* d_in, const int* in_sizes, int n_in,
                              void* d_out, int out_size, void* d_ws, size_t ws_size,
                              hipStream_t stream) {
    const float* x  = (const float*)d_in[0];
    const float* w1 = (const float*)d_in[1];
    const float* w2 = (const float*)d_in[2];
    const float* lw = (const float*)d_in[3];
    const float* lb = (const float*)d_in[4];
    float* out = (float*)d_out;

    unsigned short* pooled = (unsigned short*)d_ws;                    // 23.9 MB
    unsigned short* w2b    = (unsigned short*)((char*)d_ws + 23887872); // 400 KB

    static int lds_set = 0;
    (void)hipFuncSetAttribute((const void*)conv2_lin,
                              hipFuncAttributeMaxDynamicSharedMemorySize,
                              LDS_TOT);

    prep_w2<<<200, 256, 0, stream>>>(w2, w2b);
    conv1_pool<<<dim3(3, 256), 256, 0, stream>>>(x, w1, pooled);
    conv2_lin<<<256, 512, LDS_TOT, stream>>>(pooled, w2b, lw, lb, out);
}

// Round 4
// 82.886 us; speedup vs baseline: 16.3370x; 1.2603x over previous
//
#include <hip/hip_runtime.h>

// x[256,1,58,58] -> conv5x5(64) -> maxpool2 -> [256,64,27,27]
//   -> conv5x5(128) -> [256,128,23,23] -> linear(10) -> out[256,23,23,10] f32
//
// conv2 (95% of FLOPs): bf16 MFMA 16x16x32 implicit GEMM (unchanged from R2).
// conv1+pool: bf16 MFMA. M = conv positions ordered m = pixel*4 + quadrant,
//   so the C/D layout (row=(lane>>4)*4+j) puts each 2x2 pool window entirely
//   in one lane's 4 accs -> maxpool = 3 register fmax. K = 25 taps -> pad 32.

typedef __attribute__((ext_vector_type(8))) short bf16x8;
typedef __attribute__((ext_vector_type(4))) float f32x4;
typedef __attribute__((ext_vector_type(4))) unsigned int u32x4;

#define MFMA16(a, b, c) __builtin_amdgcn_mfma_f32_16x16x32_bf16((a), (b), (c), 0, 0, 0)

static __device__ __forceinline__ unsigned short f2bf(float f) {
    unsigned u = __builtin_bit_cast(unsigned, f);
    u += 0x7FFFu + ((u >> 16) & 1u);   // RNE
    return (unsigned short)(u >> 16);
}

// ---------------- K0: w2[oc128][ic64][25] f32 -> w2b[kk25][oc128][ic64] bf16
__global__ __launch_bounds__(256) void prep_w2(
    const float* __restrict__ w2, unsigned short* __restrict__ w2b)
{
    int e = (blockIdx.x * 256 + threadIdx.x) * 4;   // 204800 elems, 4/thread
    if (e >= 25 * 128 * 64) return;
    int kk = e / 8192;
    int r  = e - kk * 8192;
    int oc = r >> 6, ic = r & 63;
    unsigned long long pack = 0;
#pragma unroll
    for (int j = 0; j < 4; ++j) {
        unsigned short v = f2bf(w2[oc * 1600 + (ic + j) * 25 + kk]);
        pack |= (unsigned long long)v << (16 * j);
    }
    *(unsigned long long*)(w2b + e) = pack;
}

// ---------------- K1: conv1 (C=1) + maxpool2 via MFMA -> pooled[b][p][ic] bf16
__global__ __launch_bounds__(256) void conv1_pool_mfma(
    const float* __restrict__ x, const float* __restrict__ w1,
    unsigned short* __restrict__ pooled)
{
    __shared__ unsigned short xbf[3364];      // x as bf16, [58][58] row-major
    __shared__ unsigned short w1t[32 * 64];   // B: [k32][oc64], k>=25 zeroed
    const int bp = blockIdx.x, b = blockIdx.y, tid = threadIdx.x;
    const int lane = tid & 63, w = tid >> 6;
    const int l16 = lane & 15, kg = lane >> 4;

    // stage x -> bf16 (3364 = 841 float4)
    const float4* xg = (const float4*)(x + b * 3364);
    for (int i = tid; i < 841; i += 256) {
        float4 v = xg[i];
        unsigned p0 = (unsigned)f2bf(v.x) | ((unsigned)f2bf(v.y) << 16);
        unsigned p1 = (unsigned)f2bf(v.z) | ((unsigned)f2bf(v.w) << 16);
        *(uint2*)(xbf + i * 4) = make_uint2(p0, p1);
    }
    // stage w1 transposed -> [k][oc] bf16, pad k 25..31 with 0
    for (int i = tid; i < 2048; i += 256) {
        int k = i >> 6, oc = i & 63;
        w1t[i] = (k < 25) ? f2bf(w1[oc * 25 + k]) : (unsigned short)0;
    }
    __syncthreads();

    // per-lane A-tap offsets/masks for k = kg*8+j
    int koff[8];
    unsigned kmsk[8];
#pragma unroll
    for (int j = 0; j < 8; ++j) {
        int k = kg * 8 + j;
        int kh = k / 5, kw = k - 5 * kh;
        koff[j] = (k < 25) ? (kh * 58 + kw) : 0;
        kmsk[j] = (k < 25) ? 0xFFFFu : 0u;
    }

    // resident B-frags (4 oc-tiles of 16)
    bf16x8 bfrag[4];
#pragma unroll
    for (int ot = 0; ot < 4; ++ot)
#pragma unroll
        for (int j = 0; j < 8; ++j)
            bfrag[ot][j] = (short)w1t[(kg * 8 + j) * 64 + ot * 16 + l16];

    const f32x4 zero4 = {0.f, 0.f, 0.f, 0.f};
    const int tend = (bp * 46 + 46 < 183) ? bp * 46 + 46 : 183;
    for (int t = bp * 46 + w; t < tend; t += 4) {
        // A row r=l16: m = t*16+r -> pixel p = t*4 + (r>>2), quadrant q = r&3
        int p = t * 4 + (l16 >> 2);
        if (p > 728) p = 728;                      // pad rows; stores guarded
        const int q = l16 & 3;
        const int ph = p / 27, pw = p - 27 * ph;
        const int base = (2 * ph + (q >> 1)) * 58 + 2 * pw + (q & 1);

        bf16x8 afrag;
#pragma unroll
        for (int j = 0; j < 8; ++j)
            afrag[j] = (short)(xbf[base + koff[j]] & kmsk[j]);

        f32x4 acc[4];
#pragma unroll
        for (int ot = 0; ot < 4; ++ot)
            acc[ot] = MFMA16(afrag, bfrag[ot], zero4);

        // output: lane holds rows kg*4+j -> pixel pout = t*4+kg, q = j
        const int pout = t * 4 + kg;
        if (pout < 729) {
            unsigned short* dst = pooled + ((size_t)b * 729 + pout) * 64 + l16;
#pragma unroll
            for (int ot = 0; ot < 4; ++ot) {
                float m = fmaxf(fmaxf(acc[ot][0], acc[ot][1]),
                                fmaxf(acc[ot][2], acc[ot][3]));
                dst[ot * 16] = f2bf(m);
            }
        }
    }
}

// ---------------- K2: conv2 MFMA + fused linear (unchanged from R2) ---------
#define XS_OFF   0
#define WS_OFF   104976
#define WSLICE   18432
#define ECON_STR 272
#define LWT_OFF  147968
#define LDS_TOT  152320

__global__ __launch_bounds__(512, 2) void conv2_lin(
    const unsigned short* __restrict__ pooled,
    const unsigned short* __restrict__ w2b,
    const float* __restrict__ lw, const float* __restrict__ lb,
    float* __restrict__ out)
{
    extern __shared__ char lds[];
    const int b = blockIdx.x, tid = threadIdx.x;
    const int lane = tid & 63, w = tid >> 6;        // 8 waves
    const int lane16 = lane & 15, kg = lane >> 4;   // kg = 0..3
    const int ocg = w & 1, mg = w >> 1;             // 2 oc-groups x 4 m-groups
    const int oc0 = ocg * 64;                       // wave owns 64 oc (4 N-tiles)
    const int mstart = (mg == 0) ? 0 : mg * 8 + 1;  // {0,9,17,25}, 9 tiles each

    // ---- stage pooled image -> xs (144B rows) ----
    const unsigned short* src = pooled + (size_t)b * 46656;
    for (int c = tid; c < 5832; c += 512) {
        int p = c >> 3, k8 = c & 7;
        u32x4 v = *(const u32x4*)(src + c * 8);
        *(u32x4*)(lds + XS_OFF + p * 144 + k8 * 16) = v;
    }
    // ---- stage weight slice 0 ----
    for (int c = tid; c < 1024; c += 512) {
        int oc = c >> 3, k8 = c & 7;
        u32x4 v = *(const u32x4*)(w2b + c * 8);
        *(u32x4*)(lds + WS_OFF + oc * 144 + k8 * 16) = v;
    }
    // ---- stage lwT2 bf16 [o16][c128] (272B rows), pad rows zeroed ----
    for (int i = tid; i < 2048; i += 512) {
        int o = i >> 7, cc = i & 127;
        float v = (o < 10) ? lw[o * 128 + cc] : 0.f;
        *(unsigned short*)(lds + LWT_OFF + o * 272 + cc * 2) = f2bf(v);
    }

    // ---- per-lane A base byte-offsets (9 M-tiles) ----
    int abase[9];
#pragma unroll
    for (int mt = 0; mt < 9; ++mt) {
        int sp = (mstart + mt) * 16 + lane16;
        if (sp > 528) sp = 528;                     // clamp loads; stores guarded
        int oh = sp / 23, ow = sp - oh * 23;
        abase[mt] = (oh * 27 + ow) * 144 + kg * 16;
    }
    const int bbase = (oc0 + lane16) * 144 + kg * 16;  // + nt*2304 + khalf*64

    f32x4 acc[9][4];
#pragma unroll
    for (int mt = 0; mt < 9; ++mt)
#pragma unroll
        for (int nt = 0; nt < 4; ++nt)
            acc[mt][nt] = (f32x4){0.f, 0.f, 0.f, 0.f};

    __syncthreads();

    // ---- main K-loop: 25 (kh,kw) slices, dbuf weights, async-stage split ----
    for (int kk = 0; kk < 25; ++kk) {
        const int cur = kk & 1;
        const bool pref = (kk < 24);
        u32x4 st0, st1;
        const int c0 = tid, c1 = tid + 512;
        if (pref) {                       // issue loads early (hide under MFMA)
            const unsigned short* ws = w2b + (kk + 1) * 8192;
            st0 = *(const u32x4*)(ws + c0 * 8);
            st1 = *(const u32x4*)(ws + c1 * 8);
        }

        const int kh = kk / 5, kw = kk - 5 * (kk / 5);
        const int pixoffB = (kh * 27 + kw) * 144;
        const char* wbuf = lds + WS_OFF + cur * WSLICE + bbase;

        bf16x8 bf[2][4];
#pragma unroll
        for (int nt = 0; nt < 4; ++nt) {
            bf[0][nt] = *(const bf16x8*)(wbuf + nt * 2304);
            bf[1][nt] = *(const bf16x8*)(wbuf + nt * 2304 + 64);
        }
#pragma unroll
        for (int mt = 0; mt < 9; ++mt) {
            const char* ap = lds + XS_OFF + abase[mt] + pixoffB;
            bf16x8 a0 = *(const bf16x8*)(ap);
            bf16x8 a1 = *(const bf16x8*)(ap + 64);
#pragma unroll
            for (int nt = 0; nt < 4; ++nt)
                acc[mt][nt] = MFMA16(a0, bf[0][nt], acc[mt][nt]);
#pragma unroll
            for (int nt = 0; nt < 4; ++nt)
                acc[mt][nt] = MFMA16(a1, bf[1][nt], acc[mt][nt]);
        }

        if (pref) {                        // write staged regs late
            char* wd = lds + WS_OFF + (cur ^ 1) * WSLICE;
            int oc = c0 >> 3, k8 = c0 & 7;
            *(u32x4*)(wd + oc * 144 + k8 * 16) = st0;
            oc = c1 >> 3; k8 = c1 & 7;
            *(u32x4*)(wd + oc * 144 + k8 * 16) = st1;
        }
        __syncthreads();
    }

    // ---- epilogue: conv tile -> econ bf16 [544][272B rows] ----
    __syncthreads();   // xs/wsh dead for ALL waves before overwrite
#pragma unroll
    for (int mt = 0; mt < 9; ++mt) {
        const int spb = (mstart + mt) * 16 + kg * 4;
#pragma unroll
        for (int nt = 0; nt < 4; ++nt) {
            const int col = oc0 + nt * 16 + lane16;
#pragma unroll
            for (int r = 0; r < 4; ++r) {
                int sp = spb + r;
                if (sp < 529)
                    *(unsigned short*)(lds + sp * ECON_STR + col * 2) =
                        f2bf(acc[mt][nt][r]);
            }
        }
    }
    __syncthreads();

    // ---- linear via MFMA: out[sp][o] = econ[sp][c] x lwT2[o][c] + lb ----
    const float lbv = (lane16 < 10) ? lb[lane16] : 0.f;
#pragma unroll
    for (int i = 0; i < 5; ++i) {
        const int t = w + 8 * i;             // wave-uniform tile id
        if (t < 34) {
            f32x4 al = {0.f, 0.f, 0.f, 0.f};
            const char* arow = lds + (t * 16 + lane16) * ECON_STR + kg * 16;
            const char* brow = lds + LWT_OFF + lane16 * 272 + kg * 16;
#pragma unroll
            for (int ks = 0; ks < 4; ++ks) {
                bf16x8 av = *(const bf16x8*)(arow + ks * 64);
                bf16x8 bv = *(const bf16x8*)(brow + ks * 64);
                al = MFMA16(av, bv, al);
            }
            if (lane16 < 10) {
#pragma unroll
                for (int r = 0; r < 4; ++r) {
                    int sp = t * 16 + kg * 4 + r;
                    if (sp < 529)
                        out[((size_t)b * 529 + sp) * 10 + lane16] = al[r] + lbv;
                }
            }
        }
    }
}

extern "C" void kernel_launch(void* const* d_in, const int* in_sizes, int n_in,
                              void* d_out, int out_size, void* d_ws, size_t ws_size,
                              hipStream_t stream) {
    const float* x  = (const float*)d_in[0];
    const float* w1 = (const float*)d_in[1];
    const float* w2 = (const float*)d_in[2];
    const float* lw = (const float*)d_in[3];
    const float* lb = (const float*)d_in[4];
    float* out = (float*)d_out;

    unsigned short* pooled = (unsigned short*)d_ws;                     // 23.9 MB
    unsigned short* w2b    = (unsigned short*)((char*)d_ws + 23887872); // 400 KB

    (void)hipFuncSetAttribute((const void*)conv2_lin,
                              hipFuncAttributeMaxDynamicSharedMemorySize,
                              LDS_TOT);

    prep_w2<<<200, 256, 0, stream>>>(w2, w2b);
    conv1_pool_mfma<<<dim3(4, 256), 256, 0, stream>>>(x, w1, pooled);
    conv2_lin<<<256, 512, LDS_TOT, stream>>>(pooled, w2b, lw, lb, out);
}

// Round 5
// 68.082 us; speedup vs baseline: 19.8893x; 1.2174x over previous
//
#include <hip/hip_runtime.h>

// x[256,1,58,58] -> conv5x5(64) -> maxpool2 -> conv5x5(128) -> linear(10)
//   -> out[256,23,23,10] f32
//
// R5: single fused kernel per image. conv1+pool via MFMA writes the pooled
// image straight into LDS (no global round-trip). conv2 K-loop reads weights
// as register B-frags from fragment-ordered global w2c (L2-resident,
// coalesced dwordx4, reg double-buffer) -> NO barrier in the K-loop.

typedef __attribute__((ext_vector_type(8))) short bf16x8;
typedef __attribute__((ext_vector_type(4))) float f32x4;
typedef __attribute__((ext_vector_type(4))) unsigned int u32x4;

#define MFMA16(a, b, c) __builtin_amdgcn_mfma_f32_16x16x32_bf16((a), (b), (c), 0, 0, 0)

static __device__ __forceinline__ unsigned short f2bf(float f) {
    unsigned u = __builtin_bit_cast(unsigned, f);
    u += 0x7FFFu + ((u >> 16) & 1u);   // RNE
    return (unsigned short)(u >> 16);
}

// ---- K0: w2[oc128][ic64][kk25] f32 -> w2c fragment order:
//   w2c[(((kk*8 + nt)*2 + khalf)*64 + lane)*8 + j]
//     = bf16( w2[(nt*16+l16)*1600 + (khalf*32 + kg*8 + j)*25 + kk] )
// so a wave's B-frag load for (kk,nt,khalf) is base + lane*16B, coalesced.
__global__ __launch_bounds__(256) void prep_w2c(
    const float* __restrict__ w2, unsigned short* __restrict__ w2c)
{
    int t = blockIdx.x * 256 + threadIdx.x;        // 25600 threads
    if (t >= 25600) return;
    const int lane = t & 63, khalf = (t >> 6) & 1, nt = (t >> 7) & 7, kk = t >> 10;
    const int l16 = lane & 15, kg = lane >> 4;
    const int oc = nt * 16 + l16;
    const int icb = khalf * 32 + kg * 8;
    unsigned pk[4];
#pragma unroll
    for (int h = 0; h < 4; ++h) {
        unsigned short lo = f2bf(w2[oc * 1600 + (icb + 2 * h) * 25 + kk]);
        unsigned short hi = f2bf(w2[oc * 1600 + (icb + 2 * h + 1) * 25 + kk]);
        pk[h] = (unsigned)lo | ((unsigned)hi << 16);
    }
    u32x4 v; v.x = pk[0]; v.y = pk[1]; v.z = pk[2]; v.w = pk[3];
    *(u32x4*)(w2c + (size_t)t * 8) = v;
}

// ---- fused: conv1+pool (MFMA) -> xs(LDS) -> conv2 (MFMA, reg-B) -> linear
// LDS map (152320 B):
//   conv phase: xs  [0, 104976)       729 pixel rows x 144B (64 bf16 + pad)
//               xbf [104976, 111704)  58x58 input as bf16
//               w1t [111704, 115800)  [k32][oc64] bf16
//   epilogue:   econ[0, 147968)       544 sp rows x 272B
//   always:     lwT [147968, 152320)  16 o rows x 272B
#define XBF_OFF  104976
#define W1T_OFF  111704
#define ECON_STR 272
#define LWT_OFF  147968
#define LDS_TOT  152320

__global__ __launch_bounds__(512, 2) void fused_net(
    const float* __restrict__ x, const float* __restrict__ w1,
    const unsigned short* __restrict__ w2c,
    const float* __restrict__ lw, const float* __restrict__ lb,
    float* __restrict__ out)
{
    extern __shared__ char lds[];
    unsigned short* xbf = (unsigned short*)(lds + XBF_OFF);
    unsigned short* w1t = (unsigned short*)(lds + W1T_OFF);
    const int b = blockIdx.x, tid = threadIdx.x;
    const int lane = tid & 63, w = tid >> 6;        // 8 waves
    const int l16 = lane & 15, kg = lane >> 4;
    const int ocg = w & 1, mg = w >> 1;             // 2 oc-groups x 4 m-groups
    const int mstart = (mg == 0) ? 0 : mg * 8 + 1;  // {0,9,17,25}

    // ---- stage x -> xbf (bf16), w1 -> w1t [k][oc], lw -> lwT ----
    const float4* xg = (const float4*)(x + b * 3364);
    for (int i = tid; i < 841; i += 512) {
        float4 v = xg[i];
        unsigned p0 = (unsigned)f2bf(v.x) | ((unsigned)f2bf(v.y) << 16);
        unsigned p1 = (unsigned)f2bf(v.z) | ((unsigned)f2bf(v.w) << 16);
        *(uint2*)(xbf + i * 4) = make_uint2(p0, p1);
    }
    for (int i = tid; i < 2048; i += 512) {
        int k = i >> 6, oc = i & 63;
        w1t[i] = (k < 25) ? f2bf(w1[oc * 25 + k]) : (unsigned short)0;
    }
    for (int i = tid; i < 2048; i += 512) {
        int o = i >> 7, cc = i & 127;
        float v = (o < 10) ? lw[o * 128 + cc] : 0.f;
        *(unsigned short*)(lds + LWT_OFF + o * 272 + cc * 2) = f2bf(v);
    }
    __syncthreads();

    // ================= conv1 + maxpool -> xs =================
    {
        int koff[8];
        unsigned kmsk[8];
#pragma unroll
        for (int j = 0; j < 8; ++j) {
            int k = kg * 8 + j;
            int kh = k / 5, kw = k - 5 * kh;
            koff[j] = (k < 25) ? (kh * 58 + kw) : 0;
            kmsk[j] = (k < 25) ? 0xFFFFu : 0u;
        }
        bf16x8 bfrag[4];
#pragma unroll
        for (int ot = 0; ot < 4; ++ot)
#pragma unroll
            for (int j = 0; j < 8; ++j)
                bfrag[ot][j] = (short)w1t[(kg * 8 + j) * 64 + ot * 16 + l16];

        const f32x4 zero4 = {0.f, 0.f, 0.f, 0.f};
        for (int t = w; t < 183; t += 8) {
            int p = t * 4 + (l16 >> 2);
            if (p > 728) p = 728;
            const int q = l16 & 3;
            const int ph = p / 27, pw = p - 27 * ph;
            const int base = (2 * ph + (q >> 1)) * 58 + 2 * pw + (q & 1);
            bf16x8 afrag;
#pragma unroll
            for (int j = 0; j < 8; ++j)
                afrag[j] = (short)(xbf[base + koff[j]] & kmsk[j]);
            f32x4 acc1[4];
#pragma unroll
            for (int ot = 0; ot < 4; ++ot)
                acc1[ot] = MFMA16(afrag, bfrag[ot], zero4);
            const int pout = t * 4 + kg;
            if (pout < 729) {
#pragma unroll
                for (int ot = 0; ot < 4; ++ot) {
                    float m = fmaxf(fmaxf(acc1[ot][0], acc1[ot][1]),
                                    fmaxf(acc1[ot][2], acc1[ot][3]));
                    *(unsigned short*)(lds + pout * 144 + (ot * 16 + l16) * 2)
                        = f2bf(m);
                }
            }
        }
    }
    __syncthreads();   // xs complete; conv1 scratch (xbf/w1t) now dead

    // ================= conv2: barrier-free K-loop =================
    int abase[9];
#pragma unroll
    for (int mt = 0; mt < 9; ++mt) {
        int sp = (mstart + mt) * 16 + l16;
        if (sp > 528) sp = 528;
        int oh = sp / 23, ow = sp - oh * 23;
        abase[mt] = (oh * 27 + ow) * 144 + kg * 16;
    }

    f32x4 acc[9][4];
#pragma unroll
    for (int mt = 0; mt < 9; ++mt)
#pragma unroll
        for (int nt = 0; nt < 4; ++nt)
            acc[mt][nt] = (f32x4){0.f, 0.f, 0.f, 0.f};

    auto loadB = [&](bf16x8* dst, int kkv) {
#pragma unroll
        for (int i = 0; i < 4; ++i) {
#pragma unroll
            for (int hf = 0; hf < 2; ++hf) {
                const int nt = ocg * 4 + i;
                const size_t off =
                    (((size_t)kkv * 8 + nt) * 2 + hf) * 512 + lane * 8;
                dst[i * 2 + hf] = *(const bf16x8*)(w2c + off);
            }
        }
    };
    auto compute = [&](int kkv, const bf16x8* B) {
        const int kh = kkv / 5, kw = kkv - 5 * kh;
        const int pixoffB = (kh * 27 + kw) * 144;
#pragma unroll
        for (int mt = 0; mt < 9; ++mt) {
            const char* ap = lds + abase[mt] + pixoffB;
            bf16x8 a0 = *(const bf16x8*)(ap);
            bf16x8 a1 = *(const bf16x8*)(ap + 64);
#pragma unroll
            for (int i = 0; i < 4; ++i)
                acc[mt][i] = MFMA16(a0, B[i * 2 + 0], acc[mt][i]);
#pragma unroll
            for (int i = 0; i < 4; ++i)
                acc[mt][i] = MFMA16(a1, B[i * 2 + 1], acc[mt][i]);
        }
    };

    bf16x8 bA[8], bB[8];
    loadB(bA, 0);
    for (int kk = 0; kk < 25; kk += 2) {
        if (kk + 1 < 25) loadB(bB, kk + 1);     // prefetch odd slice
        compute(kk, bA);
        if (kk + 1 < 25) {
            if (kk + 2 < 25) loadB(bA, kk + 2); // prefetch next even slice
            compute(kk + 1, bB);
        }
    }

    // ================= epilogue: econ bf16 + linear MFMA =================
    __syncthreads();   // all waves done reading xs before econ overwrites it
    const int oc0 = ocg * 64;
#pragma unroll
    for (int mt = 0; mt < 9; ++mt) {
        const int spb = (mstart + mt) * 16 + kg * 4;
#pragma unroll
        for (int nt = 0; nt < 4; ++nt) {
            const int col = oc0 + nt * 16 + l16;
#pragma unroll
            for (int r = 0; r < 4; ++r) {
                int sp = spb + r;
                if (sp < 529)
                    *(unsigned short*)(lds + sp * ECON_STR + col * 2) =
                        f2bf(acc[mt][nt][r]);
            }
        }
    }
    __syncthreads();

    const float lbv = (l16 < 10) ? lb[l16] : 0.f;
#pragma unroll
    for (int i = 0; i < 5; ++i) {
        const int t = w + 8 * i;
        if (t < 34) {
            f32x4 al = {0.f, 0.f, 0.f, 0.f};
            const char* arow = lds + (t * 16 + l16) * ECON_STR + kg * 16;
            const char* brow = lds + LWT_OFF + l16 * 272 + kg * 16;
#pragma unroll
            for (int ks = 0; ks < 4; ++ks) {
                bf16x8 av = *(const bf16x8*)(arow + ks * 64);
                bf16x8 bv = *(const bf16x8*)(brow + ks * 64);
                al = MFMA16(av, bv, al);
            }
            if (l16 < 10) {
#pragma unroll
                for (int r = 0; r < 4; ++r) {
                    int sp = t * 16 + kg * 4 + r;
                    if (sp < 529)
                        out[((size_t)b * 529 + sp) * 10 + l16] = al[r] + lbv;
                }
            }
        }
    }
}

extern "C" void kernel_launch(void* const* d_in, const int* in_sizes, int n_in,
                              void* d_out, int out_size, void* d_ws, size_t ws_size,
                              hipStream_t stream) {
    const float* x  = (const float*)d_in[0];
    const float* w1 = (const float*)d_in[1];
    const float* w2 = (const float*)d_in[2];
    const float* lw = (const float*)d_in[3];
    const float* lb = (const float*)d_in[4];
    float* out = (float*)d_out;

    unsigned short* w2c = (unsigned short*)d_ws;   // 400 KB fragment-ordered

    (void)hipFuncSetAttribute((const void*)fused_net,
                              hipFuncAttributeMaxDynamicSharedMemorySize,
                              LDS_TOT);

    prep_w2c<<<100, 256, 0, stream>>>(w2, w2c);
    fused_net<<<256, 512, LDS_TOT, stream>>>(x, w1, w2c, lw, lb, out);
}

// Round 6
// 66.040 us; speedup vs baseline: 20.5044x; 1.0309x over previous
//
#include <hip/hip_runtime.h>

// x[256,1,58,58] -> conv5x5(64) -> maxpool2 -> conv5x5(128) -> linear(10)
//   -> out[256,23,23,10] f32
//
// R6: kill the 2x A-fragment LDS duplication. Each wave owns ALL 128 oc and
// 4-5 M-tiles (34 overlapping 16-row tiles cover 529 rows; tile 33 starts at
// row 513 so every A row is a real output row -> no clamps). B-fragments come
// straight from L2-resident fragment-ordered w2c on the vector-memory pipe
// (L1-broadcast across waves); LDS pipe carries only A (10 reads/wave/slice).

typedef __attribute__((ext_vector_type(8))) short bf16x8;
typedef __attribute__((ext_vector_type(4))) float f32x4;
typedef __attribute__((ext_vector_type(4))) unsigned int u32x4;

#define MFMA16(a, b, c) __builtin_amdgcn_mfma_f32_16x16x32_bf16((a), (b), (c), 0, 0, 0)

static __device__ __forceinline__ unsigned short f2bf(float f) {
    unsigned u = __builtin_bit_cast(unsigned, f);
    u += 0x7FFFu + ((u >> 16) & 1u);   // RNE
    return (unsigned short)(u >> 16);
}

// ---- K0: w2[oc128][ic64][kk25] f32 -> w2c fragment order:
//   w2c[(((kk*8 + nt)*2 + khalf)*64 + lane)*8 + j]
//     = bf16( w2[(nt*16+l16)*1600 + (khalf*32 + kg*8 + j)*25 + kk] )
__global__ __launch_bounds__(256) void prep_w2c(
    const float* __restrict__ w2, unsigned short* __restrict__ w2c)
{
    int t = blockIdx.x * 256 + threadIdx.x;        // 25600 threads
    if (t >= 25600) return;
    const int lane = t & 63, khalf = (t >> 6) & 1, nt = (t >> 7) & 7, kk = t >> 10;
    const int l16 = lane & 15, kg = lane >> 4;
    const int oc = nt * 16 + l16;
    const int icb = khalf * 32 + kg * 8;
    unsigned pk[4];
#pragma unroll
    for (int h = 0; h < 4; ++h) {
        unsigned short lo = f2bf(w2[oc * 1600 + (icb + 2 * h) * 25 + kk]);
        unsigned short hi = f2bf(w2[oc * 1600 + (icb + 2 * h + 1) * 25 + kk]);
        pk[h] = (unsigned)lo | ((unsigned)hi << 16);
    }
    u32x4 v; v.x = pk[0]; v.y = pk[1]; v.z = pk[2]; v.w = pk[3];
    *(u32x4*)(w2c + (size_t)t * 8) = v;
}

// LDS map (152320 B):
//   conv phase: xs  [0, 104976)       729 pixel rows x 144B (64 bf16 + pad)
//               xbf [104976, 111704)  58x58 input as bf16
//               w1t [111704, 115800)  [k32][oc64] bf16
//   epilogue:   econ[0, 147968)       544 sp rows x 272B
//   always:     lwT [147968, 152320)  16 o rows x 272B
#define XBF_OFF  104976
#define W1T_OFF  111704
#define ECON_STR 272
#define LWT_OFF  147968
#define LDS_TOT  152320

__global__ __launch_bounds__(512, 2) void fused_net(
    const float* __restrict__ x, const float* __restrict__ w1,
    const unsigned short* __restrict__ w2c,
    const float* __restrict__ lw, const float* __restrict__ lb,
    float* __restrict__ out)
{
    extern __shared__ char lds[];
    unsigned short* xbf = (unsigned short*)(lds + XBF_OFF);
    unsigned short* w1t = (unsigned short*)(lds + W1T_OFF);
    const int b = blockIdx.x, tid = threadIdx.x;
    const int lane = tid & 63, w = tid >> 6;        // 8 waves
    const int l16 = lane & 15, kg = lane >> 4;

    // ---- stage x -> xbf (bf16), w1 -> w1t [k][oc], lw -> lwT ----
    const float4* xg = (const float4*)(x + b * 3364);
    for (int i = tid; i < 841; i += 512) {
        float4 v = xg[i];
        unsigned p0 = (unsigned)f2bf(v.x) | ((unsigned)f2bf(v.y) << 16);
        unsigned p1 = (unsigned)f2bf(v.z) | ((unsigned)f2bf(v.w) << 16);
        *(uint2*)(xbf + i * 4) = make_uint2(p0, p1);
    }
    for (int i = tid; i < 2048; i += 512) {
        int k = i >> 6, oc = i & 63;
        w1t[i] = (k < 25) ? f2bf(w1[oc * 25 + k]) : (unsigned short)0;
    }
    for (int i = tid; i < 2048; i += 512) {
        int o = i >> 7, cc = i & 127;
        float v = (o < 10) ? lw[o * 128 + cc] : 0.f;
        *(unsigned short*)(lds + LWT_OFF + o * 272 + cc * 2) = f2bf(v);
    }
    __syncthreads();

    // ================= conv1 + maxpool -> xs =================
    {
        int koff[8];
        unsigned kmsk[8];
#pragma unroll
        for (int j = 0; j < 8; ++j) {
            int k = kg * 8 + j;
            int kh = k / 5, kw = k - 5 * kh;
            koff[j] = (k < 25) ? (kh * 58 + kw) : 0;
            kmsk[j] = (k < 25) ? 0xFFFFu : 0u;
        }
        bf16x8 bfrag[4];
#pragma unroll
        for (int ot = 0; ot < 4; ++ot)
#pragma unroll
            for (int j = 0; j < 8; ++j)
                bfrag[ot][j] = (short)w1t[(kg * 8 + j) * 64 + ot * 16 + l16];

        const f32x4 zero4 = {0.f, 0.f, 0.f, 0.f};
        for (int t = w; t < 183; t += 8) {
            int p = t * 4 + (l16 >> 2);
            if (p > 728) p = 728;
            const int q = l16 & 3;
            const int ph = p / 27, pw = p - 27 * ph;
            const int base = (2 * ph + (q >> 1)) * 58 + 2 * pw + (q & 1);
            bf16x8 afrag;
#pragma unroll
            for (int j = 0; j < 8; ++j)
                afrag[j] = (short)(xbf[base + koff[j]] & kmsk[j]);
            f32x4 acc1[4];
#pragma unroll
            for (int ot = 0; ot < 4; ++ot)
                acc1[ot] = MFMA16(afrag, bfrag[ot], zero4);
            const int pout = t * 4 + kg;
            if (pout < 729) {
#pragma unroll
                for (int ot = 0; ot < 4; ++ot) {
                    float m = fmaxf(fmaxf(acc1[ot][0], acc1[ot][1]),
                                    fmaxf(acc1[ot][2], acc1[ot][3]));
                    *(unsigned short*)(lds + pout * 144 + (ot * 16 + l16) * 2)
                        = f2bf(m);
                }
            }
        }
    }
    __syncthreads();   // xs complete; conv1 scratch (xbf/w1t) now dead

    // ================= conv2: wave = all 128 oc x 4-5 M-tiles =================
    // 34 tiles of 16 rows: tile t<33 starts at 16t; tile 33 starts at 513
    // (rows 513-528). Wave w owns tiles {w, w+8, w+16, w+24 (,w+32 if <34)}.
    const int mtc = (w < 2) ? 5 : 4;
    int abase[5];
#pragma unroll
    for (int ti = 0; ti < 5; ++ti) {
        int tile = w + 8 * ti;
        if (tile > 33) tile = w;               // unused slot (w>=2), safe addr
        const int tstart = (tile == 33) ? 513 : tile * 16;
        const int sp = tstart + l16;
        const int oh = sp / 23, ow = sp - oh * 23;
        abase[ti] = (oh * 27 + ow) * 144 + kg * 16;
    }

    f32x4 acc[5][8];
#pragma unroll
    for (int ti = 0; ti < 5; ++ti)
#pragma unroll
        for (int nt = 0; nt < 8; ++nt)
            acc[ti][nt] = (f32x4){0.f, 0.f, 0.f, 0.f};

    for (int kk = 0; kk < 25; ++kk) {
        const int kh = kk / 5, kw = kk - 5 * kh;
        const int pixoffB = (kh * 27 + kw) * 144;
        const unsigned short* wp = w2c + (size_t)kk * 8192 + lane * 8;
#pragma unroll
        for (int hf = 0; hf < 2; ++hf) {
            bf16x8 Bf[8];
#pragma unroll
            for (int nt = 0; nt < 8; ++nt)
                Bf[nt] = *(const bf16x8*)(wp + (nt * 2 + hf) * 512);
#pragma unroll
            for (int ti = 0; ti < 5; ++ti) {
                if (ti < mtc) {
                    bf16x8 a =
                        *(const bf16x8*)(lds + abase[ti] + pixoffB + hf * 64);
#pragma unroll
                    for (int nt = 0; nt < 8; ++nt)
                        acc[ti][nt] = MFMA16(a, Bf[nt], acc[ti][nt]);
                }
            }
        }
    }

    // ================= epilogue: econ bf16 + linear MFMA =================
    __syncthreads();   // all waves done reading xs before econ overwrites it
#pragma unroll
    for (int ti = 0; ti < 5; ++ti) {
        if (ti < mtc) {
            int tile = w + 8 * ti;
            if (tile > 33) tile = w;
            const int rbase = ((tile == 33) ? 513 : tile * 16) + kg * 4;
#pragma unroll
            for (int nt = 0; nt < 8; ++nt) {
                const int col = nt * 16 + l16;
#pragma unroll
                for (int r = 0; r < 4; ++r)
                    *(unsigned short*)(lds + (rbase + r) * ECON_STR + col * 2)
                        = f2bf(acc[ti][nt][r]);
            }
        }
    }
    __syncthreads();

    const float lbv = (l16 < 10) ? lb[l16] : 0.f;
#pragma unroll
    for (int i = 0; i < 5; ++i) {
        const int t = w + 8 * i;
        if (t < 34) {
            f32x4 al = {0.f, 0.f, 0.f, 0.f};
            const char* arow = lds + (t * 16 + l16) * ECON_STR + kg * 16;
            const char* brow = lds + LWT_OFF + l16 * 272 + kg * 16;
#pragma unroll
            for (int ks = 0; ks < 4; ++ks) {
                bf16x8 av = *(const bf16x8*)(arow + ks * 64);
                bf16x8 bv = *(const bf16x8*)(brow + ks * 64);
                al = MFMA16(av, bv, al);
            }
            if (l16 < 10) {
#pragma unroll
                for (int r = 0; r < 4; ++r) {
                    int sp = t * 16 + kg * 4 + r;
                    if (sp < 529)
                        out[((size_t)b * 529 + sp) * 10 + l16] = al[r] + lbv;
                }
            }
        }
    }
}

extern "C" void kernel_launch(void* const* d_in, const int* in_sizes, int n_in,
                              void* d_out, int out_size, void* d_ws, size_t ws_size,
                              hipStream_t stream) {
    const float* x  = (const float*)d_in[0];
    const float* w1 = (const float*)d_in[1];
    const float* w2 = (const float*)d_in[2];
    const float* lw = (const float*)d_in[3];
    const float* lb = (const float*)d_in[4];
    float* out = (float*)d_out;

    unsigned short* w2c = (unsigned short*)d_ws;   // 400 KB fragment-ordered

    (void)hipFuncSetAttribute((const void*)fused_net,
                              hipFuncAttributeMaxDynamicSharedMemorySize,
                              LDS_TOT);

    prep_w2c<<<100, 256, 0, stream>>>(w2, w2c);
    fused_net<<<256, 512, LDS_TOT, stream>>>(x, w1, w2c, lw, lb, out);
}